// Round 4
// baseline (242.662 us; speedup 1.0000x reference)
//
#include <hip/hip_runtime.h>
#include <hip/hip_bf16.h>

// Problem: B=16, C=512, H=W=64 -> HW=4096, fp32.
// attn[b,c,d] = sum_n q[b,c,n]*kv[b,d,n]; P = softmax_d(attn);
// info[b,c,n] = sum_d P[b,c,d]*kv[b,d,n]; out = gamma*info + img.
//
// R4 structure:
//   cast_q:  img f32 -> q16 bf16           (q16 lives in d_out, dead pre-GEMM2)
//   prep_kv: txt f32 -> kv16 bf16 + kvT bf16 (kv16 in d_out, kvT in ws)
//   gemm1:   attn partials = q16 * kv16^T  (bf16, global_load_lds pipeline)
//   softmax: partial-sum + row softmax -> P bf16
//   gemm2:   out = gamma*(kvT * P^T) + img (same GEMM template, epilogue fused)

constexpr int NB = 16;
constexpr int NC = 512;
constexpr int NHW = 4096;

typedef float f32x4 __attribute__((ext_vector_type(4)));
typedef __bf16 bf16x4 __attribute__((ext_vector_type(4)));
typedef __bf16 bf16x8 __attribute__((ext_vector_type(8)));

__device__ __forceinline__ void gload16(const void* g, void* l) {
  // async global->LDS, 16B per lane; LDS dest = wave-uniform base + lane*16
  __builtin_amdgcn_global_load_lds(
      (const __attribute__((address_space(1))) void*)g,
      (__attribute__((address_space(3))) void*)l, 16, 0, 0);
}

// ---------------------------------------------------------------------------
// Batched bf16 GEMM  D[m][n'] = sum_k A[m][k] * B[n'][k]  (both K-contiguous).
// Tile 128x128, BK=64, 512 threads = 8 waves (2Mx4N), wave tile 64x32.
// Staging: global_load_lds(16B) into double-buffered LDS, counted vmcnt(4)
// so next tile's 4 loads/wave stay in flight across the barrier (T3/T4-min).
// Swizzle: LDS dest linear; global SOURCE chunk-XORed (l&7)^(l>>3) so the
// fragment ds_read_b128 swizzle (k ^ ((r&7)<<3)) reads back the right data
// conflict-free (rule #21: same involution both sides). 0 conflicts in R1-R3.
// EPI==0: store partial D f32 to Dp[split][b][m][n']   (attn logits)
// EPI==1: out[b][n'][m] = gamma*D[m][n'] + img[...]
// ---------------------------------------------------------------------------
template <int EPI, int MDIM, int NDIM, int KDIM, int SPLITS>
__global__ __launch_bounds__(512, 4) void gemm_bt(
    const __bf16* __restrict__ A, const __bf16* __restrict__ B,
    float* __restrict__ Dp, const float* __restrict__ img,
    const float* __restrict__ gammap, float* __restrict__ outp) {
  __shared__ __bf16 sA[2][128 * 64];
  __shared__ __bf16 sB[2][128 * 64];

  const int t = threadIdx.x;
  const int lane = t & 63;
  const int wave = t >> 6;
  const int wr = wave >> 2;  // 0..1 -> M offset wr*64
  const int wc = wave & 3;   // 0..3 -> N offset wc*32

  // ---- T1: XCD-aware remap of the flat workgroup id (NWG % 8 == 0) ----
  constexpr int GX = MDIM / 128;
  constexpr int GY = NDIM / 128;
  constexpr int NWG = GX * GY * NB * SPLITS;
  constexpr int QX = NWG / 8;
  int flat = blockIdx.x + GX * (blockIdx.y + GY * blockIdx.z);
  flat = (flat & 7) * QX + (flat >> 3);
  const int bx = flat % GX;
  const int by = (flat / GX) % GY;
  const int bz = flat / (GX * GY);
  const int batch = bz / SPLITS;
  const int split = bz % SPLITS;

  const int aRow0 = bx * 128;
  const int bRow0 = by * 128;
  constexpr int KSUB = KDIM / SPLITS;
  constexpr int NT = KSUB / 64;
  const int kBeg = split * KSUB;

  // per-lane staging source: rows wave*16 + i*8 + (lane>>3); source k-chunk
  // = (lane&7) ^ (row&7), row&7 == lane>>3 here.
  const int rl = lane >> 3;
  const int csrc = ((lane & 7) ^ rl) * 8;  // bf16 units
  const __bf16* Abase = A + (long)batch * MDIM * KDIM +
                        (long)(aRow0 + wave * 16 + rl) * KDIM + csrc + kBeg;
  const __bf16* Bbase = B + (long)batch * NDIM * KDIM +
                        (long)(bRow0 + wave * 16 + rl) * KDIM + csrc + kBeg;
  const int ldsOff = wave * 16 * 64;  // wave-uniform LDS base (elems)

  auto stage = [&](int buf, int kof) {  // 4 gload_lds per wave per k-step
#pragma unroll
    for (int i = 0; i < 2; ++i) {
      gload16(Abase + kof + (long)i * 8 * KDIM, &sA[buf][ldsOff + i * 8 * 64]);
      gload16(Bbase + kof + (long)i * 8 * KDIM, &sB[buf][ldsOff + i * 8 * 64]);
    }
  };

  f32x4 acc[4][2] = {};

  auto compute_tile = [&](int buf) {
#pragma unroll
    for (int kk = 0; kk < 2; ++kk) {
      const int kb = kk * 32 + ((lane >> 4) << 3);
      bf16x8 af[4], bfr[2];
#pragma unroll
      for (int m = 0; m < 4; ++m) {
        const int r = wr * 64 + m * 16 + (lane & 15);
        af[m] = *(const bf16x8*)&sA[buf][r * 64 + (kb ^ ((r & 7) << 3))];
      }
#pragma unroll
      for (int n = 0; n < 2; ++n) {
        const int r = wc * 32 + n * 16 + (lane & 15);
        bfr[n] = *(const bf16x8*)&sB[buf][r * 64 + (kb ^ ((r & 7) << 3))];
      }
#pragma unroll
      for (int m = 0; m < 4; ++m)
#pragma unroll
        for (int n = 0; n < 2; ++n)
          acc[m][n] = __builtin_amdgcn_mfma_f32_16x16x32_bf16(
              af[m], bfr[n], acc[m][n], 0, 0, 0);
    }
  };

  // ---- pipelined K loop: stage t+1 while computing t; never drain in-loop ----
  stage(0, 0);
  int cur = 0;
#pragma unroll 1
  for (int tt = 0; tt < NT - 1; ++tt) {
    stage(cur ^ 1, (tt + 1) * 64);
    asm volatile("s_waitcnt vmcnt(4)" ::: "memory");  // tile tt landed; t+1 in flight
    __builtin_amdgcn_s_barrier();
    compute_tile(cur);
    __builtin_amdgcn_s_barrier();  // all waves done reading buf[cur]
    cur ^= 1;
  }
  asm volatile("s_waitcnt vmcnt(0)" ::: "memory");
  __builtin_amdgcn_s_barrier();
  compute_tile(cur);

  // ---- epilogue ----  C/D layout (m89): col = lane&15, row = (lane>>4)*4 + reg
  if constexpr (EPI == 0) {
    float* D = Dp + ((long)split * NB + batch) * MDIM * NDIM;
    const int m0 = aRow0 + wr * 64;
    const int n0 = bRow0 + wc * 32;
#pragma unroll
    for (int m = 0; m < 4; ++m)
#pragma unroll
      for (int n = 0; n < 2; ++n) {
        const int row0 = m0 + m * 16 + ((lane >> 4) << 2);
        const int col = n0 + n * 16 + (lane & 15);
#pragma unroll
        for (int r = 0; r < 4; ++r)
          D[(long)(row0 + r) * NDIM + col] = acc[m][n][r];
      }
  } else {
    const float g = gammap[0];
    const long obase = (long)batch * NC * NHW;
    const int sp0 = aRow0 + wr * 64;  // spatial (m)
    const int ch0 = bRow0 + wc * 32;  // channel (n')
#pragma unroll
    for (int m = 0; m < 4; ++m)
#pragma unroll
      for (int n = 0; n < 2; ++n) {
        const int sp = sp0 + m * 16 + ((lane >> 4) << 2);
        const int ch = ch0 + n * 16 + (lane & 15);
        const long idx = obase + (long)ch * NHW + sp;
        f32x4 iv = *(const f32x4*)(img + idx);
        f32x4 ov;
#pragma unroll
        for (int r = 0; r < 4; ++r) ov[r] = g * acc[m][n][r] + iv[r];
        *(f32x4*)(outp + idx) = ov;
      }
  }
}

// ---------------------------------------------------------------------------
// cast_q: img f32 -> q16 bf16, elementwise, 16B/thread stores.
// ---------------------------------------------------------------------------
__global__ __launch_bounds__(256) void cast_q(const float* __restrict__ src,
                                              __bf16* __restrict__ dst) {
  const long N = (long)NB * NC * NHW;
  const long stride = (long)gridDim.x * 256 * 8;
  for (long i = ((long)blockIdx.x * 256 + threadIdx.x) * 8; i < N; i += stride) {
    f32x4 a = *(const f32x4*)(src + i);
    f32x4 b = *(const f32x4*)(src + i + 4);
    bf16x8 h = {(__bf16)a.x, (__bf16)a.y, (__bf16)a.z, (__bf16)a.w,
                (__bf16)b.x, (__bf16)b.y, (__bf16)b.z, (__bf16)b.w};
    *(bf16x8*)(dst + i) = h;
  }
}

// ---------------------------------------------------------------------------
// prep_kv: kv[b][d][n] f32 -> kv16[b][d][n] bf16 (row-major cast) AND
//          kvT[b][n][d] bf16 (transpose). 64x64 tiles via LDS.
// ---------------------------------------------------------------------------
__global__ __launch_bounds__(256) void prep_kv(const float* __restrict__ kv,
                                               __bf16* __restrict__ kv16,
                                               __bf16* __restrict__ kvT) {
  __shared__ __bf16 tile[64 * 68];  // [d][n], pitch 68
  const int t = threadIdx.x;
  const int n0 = blockIdx.x * 64;
  const int d0 = blockIdx.y * 64;
  const long ibase = (long)blockIdx.z * NC * NHW;

  const int nc4 = (t & 15) * 4;
  const int dr0 = t >> 4;  // 0..15
#pragma unroll
  for (int i = 0; i < 4; ++i) {
    const int dr = dr0 + 16 * i;
    f32x4 v = *(const f32x4*)(kv + ibase + (long)(d0 + dr) * NHW + n0 + nc4);
    bf16x4 h = {(__bf16)v.x, (__bf16)v.y, (__bf16)v.z, (__bf16)v.w};
    *(bf16x4*)&tile[dr * 68 + nc4] = h;
    *(bf16x4*)(kv16 + ibase + (long)(d0 + dr) * NHW + n0 + nc4) = h;
  }
  __syncthreads();

  const long obase = (long)blockIdx.z * NHW * NC;
  const int nr = t >> 2;  // 0..63
  const int dc0 = t & 3;
#pragma unroll
  for (int i = 0; i < 2; ++i) {
    const int dc = dc0 + 4 * i;  // 0..7, 8 bf16 each
    bf16x8 pk;
#pragma unroll
    for (int j = 0; j < 8; ++j) pk[j] = tile[(dc * 8 + j) * 68 + nr];
    *(bf16x8*)(kvT + obase + (long)(n0 + nr) * NC + d0 + dc * 8) = pk;
  }
}

// ---------------------------------------------------------------------------
// Row softmax with split-K reduction: partials [SPLITS][b*NC=row][NC] f32
// -> P bf16. One wave per row.
// ---------------------------------------------------------------------------
template <int SPLITS>
__global__ __launch_bounds__(256) void softmax_rows(
    const float* __restrict__ attn, __bf16* __restrict__ P) {
  const int row = blockIdx.x * 4 + (threadIdx.x >> 6);
  const int lane = threadIdx.x & 63;
  const long PS = (long)NB * NC * NC;  // split stride (elements)
  const float* src = attn + (long)row * NC;

  float x[8] = {0.f, 0.f, 0.f, 0.f, 0.f, 0.f, 0.f, 0.f};
#pragma unroll
  for (int s = 0; s < SPLITS; ++s) {
    f32x4 v0 = *(const f32x4*)(src + s * PS + lane * 4);
    f32x4 v1 = *(const f32x4*)(src + s * PS + 256 + lane * 4);
#pragma unroll
    for (int r = 0; r < 4; ++r) { x[r] += v0[r]; x[4 + r] += v1[r]; }
  }

  float mx = x[0];
#pragma unroll
  for (int r = 1; r < 8; ++r) mx = fmaxf(mx, x[r]);
#pragma unroll
  for (int off = 32; off >= 1; off >>= 1) mx = fmaxf(mx, __shfl_xor(mx, off));

  float e[8], s = 0.f;
#pragma unroll
  for (int r = 0; r < 8; ++r) { e[r] = expf(x[r] - mx); s += e[r]; }
#pragma unroll
  for (int off = 32; off >= 1; off >>= 1) s += __shfl_xor(s, off);
  const float inv = 1.0f / s;

  __bf16* dst = P + (long)row * NC;
  bf16x4 h0, h1;
#pragma unroll
  for (int r = 0; r < 4; ++r) {
    h0[r] = (__bf16)(e[r] * inv);
    h1[r] = (__bf16)(e[4 + r] * inv);
  }
  *(bf16x4*)(dst + lane * 4) = h0;
  *(bf16x4*)(dst + 256 + lane * 4) = h1;
}

// ---------------------------------------------------------------------------
extern "C" void kernel_launch(void* const* d_in, const int* in_sizes, int n_in,
                              void* d_out, int out_size, void* d_ws,
                              size_t ws_size, hipStream_t stream) {
  const float* img = (const float*)d_in[0];   // q source
  const float* txt = (const float*)d_in[1];   // kv source
  const float* gamma = (const float*)d_in[2];
  float* out = (float*)d_out;

  // d_out (128 MiB) hosts the bf16 casts until GEMM2 overwrites it:
  //   [0,64MiB) q16, [64,128MiB) kv16 — both dead before gemm2 launches.
  __bf16* q16 = (__bf16*)d_out;
  __bf16* kv16 = (__bf16*)d_out + (size_t)NB * NC * NHW;

  const size_t MiB = 1024 * 1024;
  char* ws = (char*)d_ws;
  const bool big = ws_size >= 104 * MiB;  // SPLITK=2 layout needs 104 MiB

  float* attnP = (float*)ws;  // 16 MiB per split
  __bf16* P = (__bf16*)(ws + (big ? 32 : 16) * MiB);   // 8 MiB
  __bf16* kvT = (__bf16*)(ws + (big ? 40 : 24) * MiB); // 64 MiB

  // 1) bf16 prep
  cast_q<<<2048, 256, 0, stream>>>(img, q16);
  prep_kv<<<dim3(NHW / 64, NC / 64, NB), 256, 0, stream>>>(txt, kv16, kvT);

  // 2) attn partials = q16 * kv16^T  (per batch 512x512, K=4096)
  if (big)
    gemm_bt<0, NC, NC, NHW, 2><<<dim3(4, 4, NB * 2), 512, 0, stream>>>(
        q16, kv16, attnP, nullptr, nullptr, nullptr);
  else
    gemm_bt<0, NC, NC, NHW, 1><<<dim3(4, 4, NB), 512, 0, stream>>>(
        q16, kv16, attnP, nullptr, nullptr, nullptr);

  // 3) P = softmax_rows(sum of partials), bf16
  if (big)
    softmax_rows<2><<<dim3(NB * NC / 4), 256, 0, stream>>>(attnP, P);
  else
    softmax_rows<1><<<dim3(NB * NC / 4), 256, 0, stream>>>(attnP, P);

  // 4) out[b][c][n] = gamma * (kvT * P^T)[n][c] + img   (K=512)
  gemm_bt<1, NHW, NC, NC, 1><<<dim3(NHW / 128, 4, NB), 512, 0, stream>>>(
      kvT, P, nullptr, img, gamma, out);
}

// Round 5
// 216.125 us; speedup vs baseline: 1.1228x; 1.1228x over previous
//
#include <hip/hip_runtime.h>
#include <hip/hip_bf16.h>

// Problem: B=16, C=512, H=W=64 -> HW=4096, fp32.
// attn[b,c,d] = sum_n q[b,c,n]*kv[b,d,n]; P = softmax_d(attn);
// info[b,c,n] = sum_d P[b,c,d]*kv[b,d,n]; out = gamma*info + img.
//
// R5 structure:
//   prep_kv: txt f32 -> kv16 bf16 (in d_out) + kvT bf16 (in ws)
//   gemm_qk: attn partials = img(f32,reg-staged+cvt) * kv16^T (gload_lds)
//            dbuf LDS + raw barriers + T14 early-issue; SPLITK=2 -> d_out
//   softmax: partial-sum + row softmax -> P bf16 (ws)
//   gemm_pv: out = gamma*(kvT * P^T) + img ; m97 single-buffer structure,
//            32 KiB LDS -> 4 blocks/CU.

constexpr int NB = 16;
constexpr int NC = 512;
constexpr int NHW = 4096;
constexpr int QKSPLIT = 2;

typedef float f32x4 __attribute__((ext_vector_type(4)));
typedef __bf16 bf16x4 __attribute__((ext_vector_type(4)));
typedef __bf16 bf16x8 __attribute__((ext_vector_type(8)));

__device__ __forceinline__ void gload16(const void* g, void* l) {
  __builtin_amdgcn_global_load_lds(
      (const __attribute__((address_space(1))) void*)g,
      (__attribute__((address_space(3))) void*)l, 16, 0, 0);
}

// ---------------------------------------------------------------------------
// gemm_qk: D[m][n'] = sum_k A[m][k]*B[n'][k], A f32 (img), B bf16 (kv16).
// Tile 128x128, BK=64, 8 waves (2Mx4N), wave tile 64x32.
// A: reg-staged f32 -> cvt -> swizzled ds_write (R1-R3 proven mapping).
// B: global_load_lds 16B, linear LDS dest + source-XOR (R4 proven, 0 confl).
// Double-buffered; raw s_barrier; loads for t+1 issued before compute of t.
// ---------------------------------------------------------------------------
template <int SPLITS>
__global__ __launch_bounds__(512) void gemm_qk(const float* __restrict__ Af,
                                               const __bf16* __restrict__ B,
                                               float* __restrict__ Dp) {
  __shared__ __bf16 sA[2][128 * 64];
  __shared__ __bf16 sB[2][128 * 64];

  const int t = threadIdx.x;
  const int lane = t & 63;
  const int wave = t >> 6;
  const int wr = wave >> 2;
  const int wc = wave & 3;

  // XCD-aware remap (NWG = 4*4*NB*SPLITS, % 8 == 0)
  constexpr int NWG = 16 * NB * SPLITS;
  constexpr int QX = NWG / 8;
  int flat = blockIdx.x + 4 * (blockIdx.y + 4 * blockIdx.z);
  flat = (flat & 7) * QX + (flat >> 3);
  const int bx = flat & 3;
  const int by = (flat >> 2) & 3;
  const int bz = flat >> 4;
  const int batch = bz / SPLITS;
  const int split = bz % SPLITS;

  const int aRow0 = bx * 128;
  const int bRow0 = by * 128;
  constexpr int KSUB = NHW / SPLITS;
  constexpr int NT = KSUB / 64;
  const int kBeg = split * KSUB;

  // B staging (gload_lds): rows wave*16 + i*8 + (lane>>3), src chunk XOR
  const int rl = lane >> 3;
  const int csrc = ((lane & 7) ^ rl) * 8;
  const __bf16* Bbase = B + (long)batch * NC * NHW +
                        (long)(bRow0 + wave * 16 + rl) * NHW + csrc + kBeg;
  const int ldsOff = wave * 16 * 64;

  // A staging (f32 regs): k-cols c4..c4+3, rows rb + 32*i
  const int c4 = (t & 15) * 4;
  const int rb = t >> 4;
  const float* Abase =
      Af + (long)batch * NC * NHW + (long)(aRow0 + rb) * NHW + kBeg + c4;

  f32x4 ra[4];
  auto loadA = [&](int kof) {
#pragma unroll
    for (int i = 0; i < 4; ++i)
      ra[i] = *(const f32x4*)(Abase + kof + (long)(32 * i) * NHW);
  };
  auto writeA = [&](int buf) {
#pragma unroll
    for (int i = 0; i < 4; ++i) {
      const int r = rb + 32 * i;
      const int idx = r * 64 + (c4 ^ ((r & 7) << 3));
      bf16x4 h = {(__bf16)ra[i].x, (__bf16)ra[i].y, (__bf16)ra[i].z,
                  (__bf16)ra[i].w};
      *(bf16x4*)&sA[buf][idx] = h;
    }
  };
  auto stageB = [&](int buf, int kof) {
#pragma unroll
    for (int i = 0; i < 2; ++i)
      gload16(Bbase + kof + (long)(i * 8) * NHW,
              &sB[buf][ldsOff + i * 8 * 64]);
  };

  f32x4 acc[4][2] = {};
  auto compute_tile = [&](int buf) {
#pragma unroll
    for (int kk = 0; kk < 2; ++kk) {
      const int kb = kk * 32 + ((lane >> 4) << 3);
      bf16x8 af[4], bfr[2];
#pragma unroll
      for (int m = 0; m < 4; ++m) {
        const int r = wr * 64 + m * 16 + (lane & 15);
        af[m] = *(const bf16x8*)&sA[buf][r * 64 + (kb ^ ((r & 7) << 3))];
      }
#pragma unroll
      for (int n = 0; n < 2; ++n) {
        const int r = wc * 32 + n * 16 + (lane & 15);
        bfr[n] = *(const bf16x8*)&sB[buf][r * 64 + (kb ^ ((r & 7) << 3))];
      }
#pragma unroll
      for (int m = 0; m < 4; ++m)
#pragma unroll
        for (int n = 0; n < 2; ++n)
          acc[m][n] = __builtin_amdgcn_mfma_f32_16x16x32_bf16(
              af[m], bfr[n], acc[m][n], 0, 0, 0);
    }
  };

  // prologue: fully stage tile 0
  stageB(0, 0);
  loadA(0);
  asm volatile("s_waitcnt vmcnt(0)" ::: "memory");
  writeA(0);
  __syncthreads();

  int cur = 0;
#pragma unroll 1
  for (int tt = 0; tt < NT; ++tt) {
    const bool more = (tt + 1) < NT;
    if (more) {
      stageB(cur ^ 1, (tt + 1) * 64);  // async into other buffer
      loadA((tt + 1) * 64);            // f32 -> regs, latency hides under MFMA
      asm volatile("" ::: "memory");   // pin issue point
    }
    compute_tile(cur);
    if (more) {
      __builtin_amdgcn_s_barrier();  // all waves done reading buf[cur]
      asm volatile("s_waitcnt vmcnt(0)" ::: "memory");  // ra + B landed
      writeA(cur ^ 1);
      asm volatile("s_waitcnt lgkmcnt(0)" ::: "memory");
      __builtin_amdgcn_s_barrier();  // buf[cur^1] fully staged
      cur ^= 1;
    }
  }

  // epilogue: partial store. C/D layout: col=lane&15, row=(lane>>4)*4+reg
  float* D = Dp + ((long)split * NB + batch) * NC * NC;
  const int m0 = aRow0 + wr * 64;
  const int n0 = bRow0 + wc * 32;
#pragma unroll
  for (int m = 0; m < 4; ++m)
#pragma unroll
    for (int n = 0; n < 2; ++n) {
      const int row0 = m0 + m * 16 + ((lane >> 4) << 2);
      const int col = n0 + n * 16 + (lane & 15);
#pragma unroll
      for (int r = 0; r < 4; ++r)
        D[(long)(row0 + r) * NC + col] = acc[m][n][r];
    }
}

// ---------------------------------------------------------------------------
// gemm_pv: out[b][c][sp] = gamma * sum_d kvT[sp][d]*P[c][d] + img[b][c][sp].
// m97 structure: single 32 KiB LDS buffer, gload_lds both sides, syncthreads.
// A = kvT [b][4096][512], B = P [b][512][512], K=512.
// ---------------------------------------------------------------------------
__global__ __launch_bounds__(512) void gemm_pv(const __bf16* __restrict__ A,
                                               const __bf16* __restrict__ B,
                                               const float* __restrict__ img,
                                               const float* __restrict__ gammap,
                                               float* __restrict__ outp) {
  __shared__ __bf16 sA[128 * 64];
  __shared__ __bf16 sB[128 * 64];

  const int t = threadIdx.x;
  const int lane = t & 63;
  const int wave = t >> 6;
  const int wr = wave >> 2;
  const int wc = wave & 3;

  constexpr int GX = NHW / 128;  // 32
  constexpr int NWG = GX * 4 * NB;  // 2048
  constexpr int QX = NWG / 8;
  int flat = blockIdx.x + GX * (blockIdx.y + 4 * blockIdx.z);
  flat = (flat & 7) * QX + (flat >> 3);
  const int bx = flat % GX;
  const int by = (flat / GX) & 3;
  const int batch = flat / (GX * 4);

  const int aRow0 = bx * 128;
  const int bRow0 = by * 128;

  const int rl = lane >> 3;
  const int csrc = ((lane & 7) ^ rl) * 8;
  const __bf16* Abase =
      A + (long)batch * NHW * NC + (long)(aRow0 + wave * 16 + rl) * NC + csrc;
  const __bf16* Bbase =
      B + (long)batch * NC * NC + (long)(bRow0 + wave * 16 + rl) * NC + csrc;
  const int ldsOff = wave * 16 * 64;

  f32x4 acc[4][2] = {};

#pragma unroll 1
  for (int k0 = 0; k0 < NC; k0 += 64) {
#pragma unroll
    for (int i = 0; i < 2; ++i) {
      gload16(Abase + k0 + (long)(i * 8) * NC, &sA[ldsOff + i * 8 * 64]);
      gload16(Bbase + k0 + (long)(i * 8) * NC, &sB[ldsOff + i * 8 * 64]);
    }
    __syncthreads();  // compiler drains vmcnt before barrier (m97 structure)
#pragma unroll
    for (int kk = 0; kk < 2; ++kk) {
      const int kb = kk * 32 + ((lane >> 4) << 3);
      bf16x8 af[4], bfr[2];
#pragma unroll
      for (int m = 0; m < 4; ++m) {
        const int r = wr * 64 + m * 16 + (lane & 15);
        af[m] = *(const bf16x8*)&sA[r * 64 + (kb ^ ((r & 7) << 3))];
      }
#pragma unroll
      for (int n = 0; n < 2; ++n) {
        const int r = wc * 32 + n * 16 + (lane & 15);
        bfr[n] = *(const bf16x8*)&sB[r * 64 + (kb ^ ((r & 7) << 3))];
      }
#pragma unroll
      for (int m = 0; m < 4; ++m)
#pragma unroll
        for (int n = 0; n < 2; ++n)
          acc[m][n] = __builtin_amdgcn_mfma_f32_16x16x32_bf16(
              af[m], bfr[n], acc[m][n], 0, 0, 0);
    }
    __syncthreads();
  }

  // epilogue: out[b][ch][sp] = gamma*acc + img
  const float g = gammap[0];
  const long obase = (long)batch * NC * NHW;
  const int sp0 = aRow0 + wr * 64;
  const int ch0 = bRow0 + wc * 32;
#pragma unroll
  for (int m = 0; m < 4; ++m)
#pragma unroll
    for (int n = 0; n < 2; ++n) {
      const int sp = sp0 + m * 16 + ((lane >> 4) << 2);
      const int ch = ch0 + n * 16 + (lane & 15);
      const long idx = obase + (long)ch * NHW + sp;
      f32x4 iv = *(const f32x4*)(img + idx);
      f32x4 ov;
#pragma unroll
      for (int r = 0; r < 4; ++r) ov[r] = g * acc[m][n][r] + iv[r];
      *(f32x4*)(outp + idx) = ov;
    }
}

// ---------------------------------------------------------------------------
// prep_kv: kv[b][d][n] f32 -> kv16[b][d][n] bf16 AND kvT[b][n][d] bf16.
// ---------------------------------------------------------------------------
__global__ __launch_bounds__(256) void prep_kv(const float* __restrict__ kv,
                                               __bf16* __restrict__ kv16,
                                               __bf16* __restrict__ kvT) {
  __shared__ __bf16 tile[64 * 68];
  const int t = threadIdx.x;
  const int n0 = blockIdx.x * 64;
  const int d0 = blockIdx.y * 64;
  const long ibase = (long)blockIdx.z * NC * NHW;

  const int nc4 = (t & 15) * 4;
  const int dr0 = t >> 4;
#pragma unroll
  for (int i = 0; i < 4; ++i) {
    const int dr = dr0 + 16 * i;
    f32x4 v = *(const f32x4*)(kv + ibase + (long)(d0 + dr) * NHW + n0 + nc4);
    bf16x4 h = {(__bf16)v.x, (__bf16)v.y, (__bf16)v.z, (__bf16)v.w};
    *(bf16x4*)&tile[dr * 68 + nc4] = h;
    *(bf16x4*)(kv16 + ibase + (long)(d0 + dr) * NHW + n0 + nc4) = h;
  }
  __syncthreads();

  const long obase = (long)blockIdx.z * NHW * NC;
  const int nr = t >> 2;
  const int dc0 = t & 3;
#pragma unroll
  for (int i = 0; i < 2; ++i) {
    const int dc = dc0 + 4 * i;
    bf16x8 pk;
#pragma unroll
    for (int j = 0; j < 8; ++j) pk[j] = tile[(dc * 8 + j) * 68 + nr];
    *(bf16x8*)(kvT + obase + (long)(n0 + nr) * NC + d0 + dc * 8) = pk;
  }
}

// ---------------------------------------------------------------------------
// Row softmax with split-K reduction -> P bf16. One wave per row.
// ---------------------------------------------------------------------------
template <int SPLITS>
__global__ __launch_bounds__(256) void softmax_rows(
    const float* __restrict__ attn, __bf16* __restrict__ P) {
  const int row = blockIdx.x * 4 + (threadIdx.x >> 6);
  const int lane = threadIdx.x & 63;
  const long PS = (long)NB * NC * NC;
  const float* src = attn + (long)row * NC;

  float x[8] = {0.f, 0.f, 0.f, 0.f, 0.f, 0.f, 0.f, 0.f};
#pragma unroll
  for (int s = 0; s < SPLITS; ++s) {
    f32x4 v0 = *(const f32x4*)(src + s * PS + lane * 4);
    f32x4 v1 = *(const f32x4*)(src + s * PS + 256 + lane * 4);
#pragma unroll
    for (int r = 0; r < 4; ++r) { x[r] += v0[r]; x[4 + r] += v1[r]; }
  }

  float mx = x[0];
#pragma unroll
  for (int r = 1; r < 8; ++r) mx = fmaxf(mx, x[r]);
#pragma unroll
  for (int off = 32; off >= 1; off >>= 1) mx = fmaxf(mx, __shfl_xor(mx, off));

  float e[8], s = 0.f;
#pragma unroll
  for (int r = 0; r < 8; ++r) { e[r] = expf(x[r] - mx); s += e[r]; }
#pragma unroll
  for (int off = 32; off >= 1; off >>= 1) s += __shfl_xor(s, off);
  const float inv = 1.0f / s;

  __bf16* dst = P + (long)row * NC;
  bf16x4 h0, h1;
#pragma unroll
  for (int r = 0; r < 4; ++r) {
    h0[r] = (__bf16)(e[r] * inv);
    h1[r] = (__bf16)(e[4 + r] * inv);
  }
  *(bf16x4*)(dst + lane * 4) = h0;
  *(bf16x4*)(dst + 256 + lane * 4) = h1;
}

// ---------------------------------------------------------------------------
extern "C" void kernel_launch(void* const* d_in, const int* in_sizes, int n_in,
                              void* d_out, int out_size, void* d_ws,
                              size_t ws_size, hipStream_t stream) {
  const float* img = (const float*)d_in[0];
  const float* txt = (const float*)d_in[1];
  const float* gamma = (const float*)d_in[2];
  float* out = (float*)d_out;

  const size_t MiB = 1024 * 1024;
  // d_out (128 MiB) scratch until gemm_pv overwrites it:
  //   [0, 64 MiB)  kv16  (bf16)
  //   [68, 100 MiB) attnP (2 splits x 16 MiB f32)
  __bf16* kv16 = (__bf16*)d_out;
  float* attnP = (float*)((char*)d_out + 68 * MiB);
  // ws: [0,64 MiB) kvT, [64,72 MiB) P
  __bf16* kvT = (__bf16*)d_ws;
  __bf16* P = (__bf16*)((char*)d_ws + 64 * MiB);

  // 1) kv prep: bf16 row-major + transposed copies
  prep_kv<<<dim3(NHW / 64, NC / 64, NB), 256, 0, stream>>>(txt, kv16, kvT);

  // 2) attn partials = img(f32) * kv16^T  (512x512, K=4096, split 2)
  gemm_qk<QKSPLIT><<<dim3(4, 4, NB * QKSPLIT), 512, 0, stream>>>(
      img, kv16, attnP);

  // 3) P = softmax(sum of partials)
  softmax_rows<QKSPLIT><<<dim3(NB * NC / 4), 256, 0, stream>>>(attnP, P);

  // 4) out = gamma * (kvT * P^T) + img
  gemm_pv<<<dim3(NHW / 128, 4, NB), 512, 0, stream>>>(kvT, P, img, gamma, out);
}